// Round 11
// baseline (146.101 us; speedup 1.0000x reference)
//
#include <hip/hip_runtime.h>
#include <math.h>

#define QR_M 512
#define QR_N 26
#define OUTC 512
#define LDP 30   // LDS row stride (floats) for small matrices

using half8_t = __attribute__((ext_vector_type(8))) _Float16;
using f32x4   = __attribute__((ext_vector_type(4))) float;

// ---------------------------------------------------------------------------
// Fused kernel: every block redundantly computes Q (deterministic, so all
// blocks agree bit-for-bit), then grid-strides the streaming matmul.
// Replaces the serial 1-CU QR stage (~35 us) with a ~10 us parallel prologue.
//
// Prologue (per block, 256 thr):
//  Ph0: rows tid, tid+256 of A = w+1e-8 -> registers (solve inputs).
//  Ph1: Gram G = A^T A from global w (L2-hot): 91 upper-tri 2x2 col-blocks
//       x 2 row-chunks = 182 threads, 256-row loops, float2 loads.
//  Ph2: combine partials -> Gs (symmetric).
//  Ph3: 26-step Gram-domain Householder recursion, wave 0, registers+shfl
//       (round-10-proven; no cross-lane LDS deps). LAPACK slarfg signs:
//       beta=-sign(alpha)*sqrt(nsq). Produces R cols in Rt[c][j]=R[j][c].
//  Ph4: Q rows tid,tid+256 = forward-substitution solve y*R=A[row,:]
//       (cond~1.6 -> ~1e-6 err), written to LDS Qs[512][32] f16, k>=26 zero.
//  Ph5: bq fragments from Qs (MFMA B^T layout).
// Main loop: identical to round-10 dir_matmul (MFMA + LDS-transposed
// epilogue, coalesced dwordx4 stores), grid-stride over 8192 row-blocks.
// LDS: Gs+Rt+Gp+Qs+tile = 75.7 KB -> 2 blocks/CU = 8 waves/CU (fill kernel
// sustains 6.6 TB/s at ~3.5 waves/CU, so write BW is safe).
// ---------------------------------------------------------------------------
__global__ __launch_bounds__(256, 2) void fused_dir(const float* __restrict__ w,
                                                    const float* __restrict__ x,
                                                    float* __restrict__ out,
                                                    int nblk32) {
  const int tid = threadIdx.x;
  const int l   = tid & 63;
  const int wid = tid >> 6;

  __shared__ float Gs[QR_N][LDP];            // Gram (symmetric)
  __shared__ float Rt[QR_N][LDP];            // Rt[c][j] = R[j][c]
  __shared__ float Gp[2][91][4];             // Gram partials
  __shared__ __align__(16) _Float16 Qs[QR_M][32];  // Q rows, f16, k-padded
  __shared__ float tile[4][16 * 132];        // mm epilogue staging

  // ---- Ph0: own rows -> registers ----
  float a0[QR_N], a1[QR_N];
  {
    const float2* w0 = reinterpret_cast<const float2*>(w + (size_t)tid * QR_N);
    const float2* w1 = reinterpret_cast<const float2*>(w + (size_t)(tid + 256) * QR_N);
#pragma unroll
    for (int i = 0; i < 13; ++i) {
      const float2 v0 = w0[i], v1 = w1[i];
      a0[2 * i]     = v0.x + 1e-8f; a0[2 * i + 1] = v0.y + 1e-8f;
      a1[2 * i]     = v1.x + 1e-8f; a1[2 * i + 1] = v1.y + 1e-8f;
    }
  }

  // ---- Ph1: Gram partials from global w ----
  if (tid < 182) {
    const int chunk = tid / 91;          // rows chunk*256..+255
    const int blk   = tid - chunk * 91;  // upper-tri 2x2 block
    int cb = 0, rem = blk;
    while (rem >= 13 - cb) { rem -= 13 - cb; ++cb; }
    const int db = cb + rem;
    const int c0 = 2 * cb, d0 = 2 * db;
    float s00 = 0.f, s01 = 0.f, s10 = 0.f, s11 = 0.f;
    const float* wr = w + (size_t)chunk * 256 * QR_N;
    for (int r = 0; r < 256; ++r) {
      float2 ac = *reinterpret_cast<const float2*>(wr + r * QR_N + c0);
      float2 ad = *reinterpret_cast<const float2*>(wr + r * QR_N + d0);
      ac.x += 1e-8f; ac.y += 1e-8f; ad.x += 1e-8f; ad.y += 1e-8f;
      s00 += ac.x * ad.x; s01 += ac.x * ad.y;
      s10 += ac.y * ad.x; s11 += ac.y * ad.y;
    }
    Gp[chunk][blk][0] = s00; Gp[chunk][blk][1] = s01;
    Gp[chunk][blk][2] = s10; Gp[chunk][blk][3] = s11;
  }
  __syncthreads();

  // ---- Ph2: combine -> Gs ----
  if (tid < 91) {
    int cb = 0, rem = tid;
    while (rem >= 13 - cb) { rem -= 13 - cb; ++cb; }
    const int db = cb + rem;
#pragma unroll
    for (int v = 0; v < 4; ++v) {
      const float s = Gp[0][tid][v] + Gp[1][tid][v];
      const int c = 2 * cb + (v >> 1);
      const int d = 2 * db + (v & 1);
      Gs[c][d] = s;
      Gs[d][c] = s;
    }
  }
  __syncthreads();

  // ---- Ph3: recursion (wave 0, registers + shfl; round-10-proven) ----
  if (wid == 0) {
    const int c  = l;
    const int cm = (c < QR_N) ? c : (QR_N - 1);  // lanes 26..63 carry dummies
    float gcol[QR_N], tcol[QR_N], rcol[QR_N];
#pragma unroll
    for (int r = 0; r < QR_N; ++r) gcol[r] = Gs[r][cm];
#pragma unroll
    for (int r = 0; r < QR_N; ++r) tcol[r] = w[r * QR_N + cm] + 1e-8f;
#pragma unroll
    for (int r = 0; r < QR_N; ++r) rcol[r] = 0.0f;

#pragma unroll
    for (int j = 0; j < QR_N; ++j) {
      float tg = gcol[j];
#pragma unroll
      for (int r = 0; r < QR_N; ++r) {
        if (r < j) tg -= __shfl(rcol[r], j) * rcol[r];
      }
      const float nsq   = __shfl(tg, j);
      const float alpha = __shfl(tcol[j], j);
      const float norm  = sqrtf(nsq);
      const float beta  = (alpha >= 0.0f) ? -norm : norm;  // -sign(alpha)*norm
      const float tau   = (beta - alpha) / beta;
      const float scale = 1.0f / (alpha - beta);
      const float wc    = (tg - beta * tcol[j]) * scale;
      const float tw    = (c > j) ? (tau * wc) : 0.0f;
      tcol[j] -= tw;
      rcol[j]  = (c == j) ? beta : tcol[j];
#pragma unroll
      for (int rr = 0; rr < QR_N; ++rr) {
        if (rr > j) {
          const float vtop = __shfl(tcol[rr], j) * scale;
          tcol[rr] -= tw * vtop;
        }
      }
      if (c >= j && c < QR_N) Rt[c][j] = rcol[j];  // write-only LDS
    }
  }
  __syncthreads();

  // ---- Ph4: solve 2 rows -> Qs (f16) ----
  {
    float rinv[QR_N];
#pragma unroll
    for (int cc = 0; cc < QR_N; ++cc) rinv[cc] = 1.0f / Rt[cc][cc];

    float y0[QR_N], y1[QR_N];
#pragma unroll
    for (int cc = 0; cc < QR_N; ++cc) { y0[cc] = a0[cc]; y1[cc] = a1[cc]; }
#pragma unroll
    for (int cc = 0; cc < QR_N; ++cc) {
      float s0 = y0[cc], s1 = y1[cc];
      int k = 0;
#pragma unroll
      for (; k + 1 < cc; k += 2) {
        const float2 rk = *reinterpret_cast<const float2*>(&Rt[cc][k]);  // bcast
        s0 -= y0[k] * rk.x + y0[k + 1] * rk.y;
        s1 -= y1[k] * rk.x + y1[k + 1] * rk.y;
      }
      if (k < cc) { const float rk = Rt[cc][k]; s0 -= y0[k] * rk; s1 -= y1[k] * rk; }
      y0[cc] = s0 * rinv[cc];
      y1[cc] = s1 * rinv[cc];
    }

    half8_t h[4];
#pragma unroll
    for (int e = 0; e < 8; ++e) h[0][e] = (_Float16)y0[e];
#pragma unroll
    for (int e = 0; e < 8; ++e) h[1][e] = (_Float16)y0[8 + e];
#pragma unroll
    for (int e = 0; e < 8; ++e) h[2][e] = (_Float16)y0[16 + e];
    h[3][0] = (_Float16)y0[24]; h[3][1] = (_Float16)y0[25];
#pragma unroll
    for (int e = 2; e < 8; ++e) h[3][e] = (_Float16)0.0f;
    half8_t* q0 = reinterpret_cast<half8_t*>(&Qs[tid][0]);
    q0[0] = h[0]; q0[1] = h[1]; q0[2] = h[2]; q0[3] = h[3];

#pragma unroll
    for (int e = 0; e < 8; ++e) h[0][e] = (_Float16)y1[e];
#pragma unroll
    for (int e = 0; e < 8; ++e) h[1][e] = (_Float16)y1[8 + e];
#pragma unroll
    for (int e = 0; e < 8; ++e) h[2][e] = (_Float16)y1[16 + e];
    h[3][0] = (_Float16)y1[24]; h[3][1] = (_Float16)y1[25];
#pragma unroll
    for (int e = 2; e < 8; ++e) h[3][e] = (_Float16)0.0f;
    half8_t* q1 = reinterpret_cast<half8_t*>(&Qs[tid + 256][0]);
    q1[0] = h[0]; q1[1] = h[1]; q1[2] = h[2]; q1[3] = h[3];
  }
  __syncthreads();

  // ---- Ph5: bq fragments from Qs ----
  const int rloc  = l & 15;
  const int grp   = l >> 4;
  const int k0    = grp * 8;
  const int rhalf = (wid >> 1) * 16;
  const int chalf = (wid & 1) * 256;
  const int t2b   = (wid & 1) * 16;
  float* tw = tile[wid];

  half8_t bq[16];
#pragma unroll
  for (int t2 = 0; t2 < 16; ++t2)
    bq[t2] = *reinterpret_cast<const half8_t*>(&Qs[(t2b + t2) * 16 + rloc][k0]);

  // ---- Main loop: streaming MFMA matmul (round-10 body, unchanged) ----
  for (int rb = blockIdx.x; rb < nblk32; rb += gridDim.x) {
    const int row = rb * 32 + rhalf + rloc;
    half8_t av;
    const float* xp = x + (size_t)row * QR_N + k0;
    if (grp < 3) {
#pragma unroll
      for (int e = 0; e < 4; ++e) {
        float2 v = *reinterpret_cast<const float2*>(xp + 2 * e);
        av[2 * e]     = (_Float16)v.x;
        av[2 * e + 1] = (_Float16)v.y;
      }
    } else {
      float2 v = *reinterpret_cast<const float2*>(xp);
      av[0] = (_Float16)v.x; av[1] = (_Float16)v.y;
#pragma unroll
      for (int e = 2; e < 8; ++e) av[e] = (_Float16)0.0f;
    }

#pragma unroll
    for (int cc = 0; cc < 2; ++cc) {
#pragma unroll
      for (int tt = 0; tt < 8; ++tt) {
        f32x4 acc = {0.0f, 0.0f, 0.0f, 0.0f};
        acc = __builtin_amdgcn_mfma_f32_16x16x32_f16(av, bq[cc * 8 + tt], acc, 0, 0, 0);
#pragma unroll
        for (int j = 0; j < 4; ++j)
          tw[(grp * 4 + j) * 132 + tt * 16 + rloc] = acc[j];
      }
      __syncthreads();
#pragma unroll
      for (int it = 0; it < 8; ++it) {
        const int r  = it * 2 + (l >> 5);
        const int cg = l & 31;
        f32x4 v = *reinterpret_cast<const f32x4*>(&tw[r * 132 + 4 * cg]);
        *reinterpret_cast<f32x4*>(
            out + (size_t)(rb * 32 + rhalf + r) * OUTC + chalf + cc * 128 + 4 * cg) = v;
      }
      __syncthreads();
    }
  }
}

extern "C" void kernel_launch(void* const* d_in, const int* in_sizes, int n_in,
                              void* d_out, int out_size, void* d_ws, size_t ws_size,
                              hipStream_t stream) {
  const float* input  = (const float*)d_in[0];   // [B, 26] f32
  const float* weight = (const float*)d_in[1];   // [512, 26] f32
  float* out = (float*)d_out;                    // [B, 512] f32

  const int B = in_sizes[0] / QR_N;              // 262144
  const int nblk32 = B / 32;                     // 8192

  fused_dir<<<512, 256, 0, stream>>>(weight, input, out, nblk32);
}

// Round 12
// 143.732 us; speedup vs baseline: 1.0165x; 1.0165x over previous
//
#include <hip/hip_runtime.h>
#include <math.h>

#define QR_M 512
#define QR_N 26
#define OUTC 512
#define LDP 30

using half8_t = __attribute__((ext_vector_type(8))) _Float16;
using f32x4   = __attribute__((ext_vector_type(4))) float;

// ---------------------------------------------------------------------------
// K0: partial Gram. Block b sums rows 32b..32b+31 of A = w+1e-8 into
// gp[b][351] (upper-tri pairs). 16 blocks in parallel (was serial on 1 CU).
// ---------------------------------------------------------------------------
__global__ __launch_bounds__(448) void gram_part(const float* __restrict__ w,
                                                 float* __restrict__ gp) {
  __shared__ float Ab[32][27];
  const int tid = threadIdx.x;
  const int b   = blockIdx.x;
  if (tid < 416) {
    const int r  = tid / 13;
    const int c2 = tid - r * 13;
    const float2 v = *reinterpret_cast<const float2*>(
        w + (size_t)(b * 32 + r) * QR_N + 2 * c2);
    Ab[r][2 * c2]     = v.x + 1e-8f;
    Ab[r][2 * c2 + 1] = v.y + 1e-8f;
  }
  __syncthreads();
  if (tid < 351) {
    int cb = 0, rem = tid;
    while (rem >= QR_N - cb) { rem -= QR_N - cb; ++cb; }
    const int d = cb + rem;
    float s = 0.0f;
#pragma unroll
    for (int r = 0; r < 32; ++r) s += Ab[r][cb] * Ab[r][d];
    gp[b * 351 + tid] = s;
  }
}

// ---------------------------------------------------------------------------
// K1: one wave. Combine Gram partials -> Gs; round-10-proven regs+shfl
// Householder recursion (LAPACK slarfg signs) -> R columns in rcol[] regs;
// then Rinv by back-substitution with UNIFORM loop bounds (all compile-time
// indices; R[k][m] = shfl(rcol[k], m); lanes c>=26 naturally produce zero
// columns). Emits f16 Rinv[32][32], rows/cols >=26 zeroed, row-major
// (B-fragment layout for K2's X' = X * Rinv^T MFMA).
// ---------------------------------------------------------------------------
__global__ __launch_bounds__(64) void qr_small(const float* __restrict__ w,
                                               const float* __restrict__ gp,
                                               _Float16* __restrict__ rinv16) {
  __shared__ float Gs[QR_N][LDP];
  const int l = threadIdx.x;

  // combine 16 partials per pair (fixed order -> deterministic)
#pragma unroll
  for (int s = 0; s < 6; ++s) {
    const int p = l + 64 * s;
    if (p < 351) {
      float acc = 0.0f;
#pragma unroll
      for (int b = 0; b < 16; ++b) acc += gp[b * 351 + p];
      int cb = 0, rem = p;
      while (rem >= QR_N - cb) { rem -= QR_N - cb; ++cb; }
      const int d = cb + rem;
      Gs[cb][d] = acc;
      Gs[d][cb] = acc;
    }
  }
  __syncthreads();

  // recursion: lane c = column c (round-10 Ph3, Rt writes removed)
  const int c  = l;
  const int cm = (c < QR_N) ? c : (QR_N - 1);  // lanes 26..63 carry dummies
  float gcol[QR_N], tcol[QR_N], rcol[QR_N];
#pragma unroll
  for (int r = 0; r < QR_N; ++r) gcol[r] = Gs[r][cm];
#pragma unroll
  for (int r = 0; r < QR_N; ++r) tcol[r] = w[r * QR_N + cm] + 1e-8f;
#pragma unroll
  for (int r = 0; r < QR_N; ++r) rcol[r] = 0.0f;

#pragma unroll
  for (int j = 0; j < QR_N; ++j) {
    float tg = gcol[j];
#pragma unroll
    for (int r = 0; r < QR_N; ++r) {
      if (r < j) tg -= __shfl(rcol[r], j) * rcol[r];
    }
    const float nsq   = __shfl(tg, j);
    const float alpha = __shfl(tcol[j], j);
    const float norm  = sqrtf(nsq);
    const float beta  = (alpha >= 0.0f) ? -norm : norm;  // -sign(alpha)*norm
    const float tau   = (beta - alpha) / beta;
    const float scale = 1.0f / (alpha - beta);
    const float wc    = (tg - beta * tcol[j]) * scale;
    const float tw    = (c > j) ? (tau * wc) : 0.0f;
    tcol[j] -= tw;
    rcol[j]  = (c == j) ? beta : tcol[j];
#pragma unroll
    for (int rr = 0; rr < QR_N; ++rr) {
      if (rr > j) {
        const float vtop = __shfl(tcol[rr], j) * scale;
        tcol[rr] -= tw * vtop;
      }
    }
  }
  // rcol[j] on lane m>=j holds R[j][m]; lower triangle never read below.

  // Rinv column c: solve R z = e_c, k = 25..0 (uniform bounds, static idx)
  float z[QR_N];
#pragma unroll
  for (int k = QR_N - 1; k >= 0; --k) {
    float s = (c == k) ? 1.0f : 0.0f;
#pragma unroll
    for (int m = k + 1; m < QR_N; ++m) s -= __shfl(rcol[k], m) * z[m];
    z[k] = s / __shfl(rcol[k], k);
  }
  // lane c (>=26): e_c never hit -> z == 0 -> zero columns automatically.
  if (c < 32) {
#pragma unroll
    for (int k = 0; k < QR_N; ++k) rinv16[k * 32 + c] = (_Float16)z[k];
#pragma unroll
    for (int k = QR_N; k < 32; ++k) rinv16[k * 32 + c] = (_Float16)0.0f;
  }
}

// ---------------------------------------------------------------------------
// K2: out = (X * Rinv^T) * A^T, all-MFMA. Per 16-row tile:
//   p = mfma(f16(X), rinvfrag)  -> X' (2 N-tiles), cast f16, stage in
//   per-wave-private xs[16][40] (16B-aligned b128 readback, <=2-way banks,
//   wave-local RAW -> no barrier), then 16 MFMA vs bq = f16(w+1e-8) and the
//   proven LDS-transposed epilogue (coalesced dwordx4 stores).
// LDS 33.8 + 5.1 = 38.9 KB -> 4 blocks/CU. grid 1024 (prologue once per
// resident block).
// ---------------------------------------------------------------------------
__global__ __launch_bounds__(256, 4) void dir_matmul(const float* __restrict__ x,
                                                     const float* __restrict__ w,
                                                     const _Float16* __restrict__ rinv16,
                                                     float* __restrict__ out,
                                                     int nblk32) {
  const int tid   = threadIdx.x;
  const int wid   = tid >> 6;
  const int l     = tid & 63;
  const int rloc  = l & 15;
  const int grp   = l >> 4;
  const int k0    = grp * 8;
  const int rhalf = (wid >> 1) * 16;
  const int chalf = (wid & 1) * 256;
  const int t2b   = (wid & 1) * 16;

  __shared__ float tile[4][16 * 132];
  __shared__ __align__(16) _Float16 xs[4][16][40];
  float* tw = tile[wid];

  // Rinv B-fragments (2 N-tiles) from global (2 KB, L2-hot)
  half8_t rv[2];
#pragma unroll
  for (int t = 0; t < 2; ++t)
    rv[t] = *reinterpret_cast<const half8_t*>(rinv16 + (size_t)(t * 16 + rloc) * 32 + k0);

  // bq = f16(w + 1e-8), B^T fragment layout (same masking as X loads)
  half8_t bq[16];
#pragma unroll
  for (int t2 = 0; t2 < 16; ++t2) {
    const float* wp = w + (size_t)((t2b + t2) * 16 + rloc) * QR_N + k0;
    half8_t h;
    if (grp < 3) {
#pragma unroll
      for (int e = 0; e < 4; ++e) {
        const float2 v = *reinterpret_cast<const float2*>(wp + 2 * e);
        h[2 * e]     = (_Float16)(v.x + 1e-8f);
        h[2 * e + 1] = (_Float16)(v.y + 1e-8f);
      }
    } else {
      const float2 v = *reinterpret_cast<const float2*>(wp);
      h[0] = (_Float16)(v.x + 1e-8f); h[1] = (_Float16)(v.y + 1e-8f);
#pragma unroll
      for (int e = 2; e < 8; ++e) h[e] = (_Float16)0.0f;
    }
    bq[t2] = h;
  }

  for (int rb = blockIdx.x; rb < nblk32; rb += gridDim.x) {
    const int row = rb * 32 + rhalf + rloc;
    half8_t av;
    const float* xp = x + (size_t)row * QR_N + k0;
    if (grp < 3) {
#pragma unroll
      for (int e = 0; e < 4; ++e) {
        const float2 v = *reinterpret_cast<const float2*>(xp + 2 * e);
        av[2 * e]     = (_Float16)v.x;
        av[2 * e + 1] = (_Float16)v.y;
      }
    } else {
      const float2 v = *reinterpret_cast<const float2*>(xp);
      av[0] = (_Float16)v.x; av[1] = (_Float16)v.y;
#pragma unroll
      for (int e = 2; e < 8; ++e) av[e] = (_Float16)0.0f;
    }

    // X' = X * Rinv^T  (C/D: col=lane&15 -> X' k-index, row=(lane>>4)*4+j)
    f32x4 p0 = {0.f, 0.f, 0.f, 0.f}, p1 = {0.f, 0.f, 0.f, 0.f};
    p0 = __builtin_amdgcn_mfma_f32_16x16x32_f16(av, rv[0], p0, 0, 0, 0);
    p1 = __builtin_amdgcn_mfma_f32_16x16x32_f16(av, rv[1], p1, 0, 0, 0);
#pragma unroll
    for (int j = 0; j < 4; ++j) {
      xs[wid][grp * 4 + j][rloc]      = (_Float16)p0[j];
      xs[wid][grp * 4 + j][16 + rloc] = (_Float16)p1[j];
    }
    // wave-local RAW: compiler inserts lgkmcnt wait; xs is per-wave private
    const half8_t av2 = *reinterpret_cast<const half8_t*>(&xs[wid][rloc][k0]);

#pragma unroll
    for (int cc = 0; cc < 2; ++cc) {
#pragma unroll
      for (int tt = 0; tt < 8; ++tt) {
        f32x4 acc = {0.f, 0.f, 0.f, 0.f};
        acc = __builtin_amdgcn_mfma_f32_16x16x32_f16(av2, bq[cc * 8 + tt], acc, 0, 0, 0);
#pragma unroll
        for (int j = 0; j < 4; ++j)
          tw[(grp * 4 + j) * 132 + tt * 16 + rloc] = acc[j];
      }
      __syncthreads();
#pragma unroll
      for (int it = 0; it < 8; ++it) {
        const int r  = it * 2 + (l >> 5);
        const int cg = l & 31;
        const f32x4 v = *reinterpret_cast<const f32x4*>(&tw[r * 132 + 4 * cg]);
        *reinterpret_cast<f32x4*>(
            out + (size_t)(rb * 32 + rhalf + r) * OUTC + chalf + cc * 128 + 4 * cg) = v;
      }
      __syncthreads();
    }
  }
}

extern "C" void kernel_launch(void* const* d_in, const int* in_sizes, int n_in,
                              void* d_out, int out_size, void* d_ws, size_t ws_size,
                              hipStream_t stream) {
  const float* input  = (const float*)d_in[0];   // [B, 26] f32
  const float* weight = (const float*)d_in[1];   // [512, 26] f32
  float* out = (float*)d_out;                    // [B, 512] f32

  float*     gp     = (float*)d_ws;                        // 16*351 f32 = 22.5 KB
  _Float16*  rinv16 = (_Float16*)((char*)d_ws + 24576);    // [32][32] f16 = 2 KB

  const int B = in_sizes[0] / QR_N;              // 262144
  const int nblk32 = B / 32;                     // 8192

  gram_part<<<16, 448, 0, stream>>>(weight, gp);
  qr_small<<<1, 64, 0, stream>>>(weight, gp, rinv16);
  dir_matmul<<<1024, 256, 0, stream>>>(input, weight, rinv16, out, nblk32);
}